// Round 1
// baseline (9353.182 us; speedup 1.0000x reference)
//
#include <hip/hip_runtime.h>
#include <math.h>

// DistilBertEncoder on MI355X — round 1: correctness-first, ALL-fp32 (vector ALU).
// Rationale: per-token expert argmax is discretely sensitive (gaps ~1e-5 exist among
// 98K argmaxes); bf16 hidden-state drift would flip expert routing => errors ~0.3-1.0
// >> 0.107 threshold. fp32 keeps drift ~1e-6 (same order as jax-vs-np ref).
// Top-k masks are reproduced BIT-EXACTLY via 4-pass radix select in monotone key space.
//
// Workspace layout (~176 MB): qkv (37.7M) | ctx | attn_out | tmp (12.6M ea) | inter (50.3M)
// | masked W qkv (21.2M) | masked W i (28.3M) | radix hist/state | expert ids/perm/meta.

#define NLAYER 6
#define NB 8
#define NS 512
#define ND 768
#define NF 3072
#define NHEAD 12
#define NT_ 4096          // tokens = NB*NS
#define NEXP 3
#define NQ 589824         // ND*ND
#define NIMASK 2359296    // NF*ND
#define NCHUNK 36
#define GBM 128
#define GBN 128
#define GBK 16
#define MAXT 35           // max grouped M-tiles: 32 + 3 slack

typedef unsigned int uint;

__device__ __forceinline__ uint keyf(float f) {
  uint b = __float_as_uint(f);
  return (b & 0x80000000u) ? ~b : (b | 0x80000000u);  // monotone float->uint
}

// ---------------- radix select (j-th largest) over 72 masks ----------------
__global__ void radix_init(uint* __restrict__ hist, uint* __restrict__ pref,
                           uint* __restrict__ jrem) {
  int t = blockIdx.x * blockDim.x + threadIdx.x;
  if (t < 72 * 256) hist[t] = 0u;
  if (t < 72) { pref[t] = 0u; jrem[t] = (t < 54) ? (NQ / 2) : (NIMASK / 2); }
}

__global__ void radix_hist(const float* __restrict__ qms, const float* __restrict__ kms,
                           const float* __restrict__ vms, const float* __restrict__ ims,
                           const uint* __restrict__ pref, uint* __restrict__ hist, int pass) {
  __shared__ uint lh[256];
  int mid = blockIdx.x / NCHUNK, chunk = blockIdx.x % NCHUNK;
  const float* ptr; int n;
  if (mid < 54) {
    int p = mid / 18, r = mid % 18;                    // r = l*3+m
    ptr = (p == 0 ? qms : (p == 1 ? kms : vms)) + (size_t)r * NQ;
    n = NQ;
  } else {
    int r = mid - 54;
    ptr = ims + (size_t)r * NIMASK;
    n = NIMASK;
  }
  lh[threadIdx.x] = 0u;
  __syncthreads();
  int per = (n + NCHUNK - 1) / NCHUNK;
  int s = chunk * per, e = min(n, s + per);
  uint pr = pref[mid];
  int sh = 24 - 8 * pass;
  for (int i = s + threadIdx.x; i < e; i += blockDim.x) {
    uint u = keyf(ptr[i]);
    bool match = (pass == 0) || (((u ^ pr) >> (sh + 8)) == 0);
    if (match) atomicAdd(&lh[(u >> sh) & 255u], 1u);
  }
  __syncthreads();
  if (lh[threadIdx.x]) atomicAdd(&hist[mid * 256 + threadIdx.x], lh[threadIdx.x]);
}

__global__ void radix_resolve(uint* __restrict__ hist, uint* __restrict__ pref,
                              uint* __restrict__ jrem, int pass) {
  int mid = threadIdx.x;
  if (mid >= 72) return;
  uint* h = hist + mid * 256;
  uint cum = 0, j = jrem[mid];
  int sh = 24 - 8 * pass;
  for (int b = 255; b >= 0; --b) {
    uint c = h[b];
    if (cum + c >= j) { pref[mid] |= ((uint)b) << sh; jrem[mid] = j - cum; break; }
    cum += c;
  }
  for (int b = 0; b < 256; ++b) h[b] = 0u;  // zero for next pass
}

// ------------- build masked weights: mw = (key(ms) >= thr) ? W : 0 -------------
__global__ void build_mw(const float* __restrict__ ms, const float* __restrict__ W,
                         const uint* __restrict__ pref, int mid0,
                         float* __restrict__ mw, int n) {
  int m = blockIdx.y;
  uint th = pref[mid0 + m];
  const float4* ms4 = (const float4*)(ms + (size_t)m * n);
  const float4* W4 = (const float4*)W;
  float4* mw4 = (float4*)(mw + (size_t)m * n);
  int n4 = n >> 2;
  int stride = gridDim.x * blockDim.x;
  for (int i = blockIdx.x * blockDim.x + threadIdx.x; i < n4; i += stride) {
    float4 sv = ms4[i], wv = W4[i], o;
    o.x = (keyf(sv.x) >= th) ? wv.x : 0.0f;
    o.y = (keyf(sv.y) >= th) ? wv.y : 0.0f;
    o.z = (keyf(sv.z) >= th) ? wv.z : 0.0f;
    o.w = (keyf(sv.w) >= th) ? wv.w : 0.0f;
    mw4[i] = o;
  }
}

// ---------------- gating: argmax_m (x . gw_m + gb_m), first-max wins ----------------
template <int NPROJ>
__global__ void gate_kernel(const float* __restrict__ x,
                            const float* __restrict__ gw0, const float* __restrict__ gw1,
                            const float* __restrict__ gw2,
                            const float* __restrict__ gb0, const float* __restrict__ gb1,
                            const float* __restrict__ gb2,
                            int* __restrict__ e0, int* __restrict__ e1, int* __restrict__ e2) {
  int t = blockIdx.x;
  int lane = threadIdx.x;  // 64 threads
  const float* xr = x + (size_t)t * ND;
  float s[NPROJ * 3];
#pragma unroll
  for (int i = 0; i < NPROJ * 3; ++i) s[i] = 0.f;
  const float* gws[3] = {gw0, gw1, gw2};
  for (int c = lane; c < ND; c += 64) {
    float xv = xr[c];
#pragma unroll
    for (int p = 0; p < NPROJ; ++p)
#pragma unroll
      for (int m = 0; m < 3; ++m) s[p * 3 + m] += xv * gws[p][m * ND + c];
  }
#pragma unroll
  for (int i = 0; i < NPROJ * 3; ++i) {
    float v = s[i];
    v += __shfl_down(v, 32, 64); v += __shfl_down(v, 16, 64);
    v += __shfl_down(v, 8, 64);  v += __shfl_down(v, 4, 64);
    v += __shfl_down(v, 2, 64);  v += __shfl_down(v, 1, 64);
    s[i] = v;
  }
  if (lane == 0) {
    const float* gbs[3] = {gb0, gb1, gb2};
    int* eo[3] = {e0, e1, e2};
#pragma unroll
    for (int p = 0; p < NPROJ; ++p) {
      float g0 = s[p * 3 + 0] + gbs[p][0];
      float g1 = s[p * 3 + 1] + gbs[p][1];
      float g2 = s[p * 3 + 2] + gbs[p][2];
      int e = 0; float gm = g0;
      if (g1 > gm) { e = 1; gm = g1; }
      if (g2 > gm) { e = 2; }
      eo[p][t] = e;
    }
  }
}

// ------------- partition tokens by expert -> perm + tile metadata -------------
__global__ void partition_kernel(const int* __restrict__ e_all, int* __restrict__ perm_all,
                                 int* __restrict__ meta_all, int pbase) {
  int p = pbase + blockIdx.x;
  const int* e = e_all + (size_t)p * NT_;
  int* perm = perm_all + (size_t)p * NT_;
  int* meta = meta_all + (size_t)p * 128;
  __shared__ int cnt[NEXP], base[NEXP], cur[NEXP];
  if (threadIdx.x < NEXP) cnt[threadIdx.x] = 0;
  __syncthreads();
  for (int t = threadIdx.x; t < NT_; t += blockDim.x) atomicAdd(&cnt[e[t]], 1);
  __syncthreads();
  if (threadIdx.x == 0) {
    base[0] = 0; base[1] = cnt[0]; base[2] = cnt[0] + cnt[1];
    cur[0] = base[0]; cur[1] = base[1]; cur[2] = base[2];
    int nt = 0;
    for (int m = 0; m < NEXP; ++m) {
      int c = cnt[m], st = base[m];
      for (int j = 0; j < c; j += GBM) {
        meta[1 + nt * 3 + 0] = m;
        meta[1 + nt * 3 + 1] = st + j;
        meta[1 + nt * 3 + 2] = min(GBM, c - j);
        ++nt;
      }
    }
    meta[0] = nt;
  }
  __syncthreads();
  for (int t = threadIdx.x; t < NT_; t += blockDim.x) {
    int pos = atomicAdd(&cur[e[t]], 1);
    perm[pos] = t;
  }
}

// ------------- fp32 GEMM: Y[t][n] = X[t][:] . W[n][:] (+bias,+resid,ACT) -------------
// ACT: 0=none, 1=gelu(exact).  NZ=3 batches q,k,v via blockIdx.z.
// Grouped mode (metaAll!=0): rows gathered through perm, per-tile expert weight.
template <int ACT, int NZ>
__global__ __launch_bounds__(256, 2) void gemm_xt(
    const float* __restrict__ X, const float* __restrict__ Wall,
    const float* __restrict__ bias0, const float* __restrict__ bias1,
    const float* __restrict__ bias2, const float* __restrict__ resid,
    float* __restrict__ Y, int M, int N, int K,
    const int* __restrict__ permAll, const int* __restrict__ metaAll) {
  __shared__ float As[GBK][GBM + 4];
  __shared__ float Bs[GBK][GBN + 4];
  int tid = threadIdx.x;
  int bx = blockIdx.x, by = blockIdx.y;
  int z = (NZ > 1) ? blockIdx.z : 0;
  const float* W = Wall + (size_t)z * NEXP * (size_t)N * K;
  const float* bias = (NZ > 1) ? (z == 0 ? bias0 : (z == 1 ? bias1 : bias2)) : bias0;
  float* Yz = Y + (size_t)z * (size_t)M * N;
  const int* perm = permAll ? (permAll + (size_t)z * NT_) : (const int*)0;
  int expert = 0, start, cnt;
  if (metaAll) {
    const int* meta = metaAll + (size_t)z * 128;
    int nt = meta[0];
    if (bx >= nt) return;
    expert = meta[1 + bx * 3 + 0];
    start = meta[1 + bx * 3 + 1];
    cnt = meta[1 + bx * 3 + 2];
  } else {
    start = bx * GBM;
    cnt = min(GBM, M - start);
  }
  W += (size_t)expert * (size_t)N * K;
  int n0 = by * GBN;
  int tx = tid & 15, ty = tid >> 4;
  float acc[8][8];
#pragma unroll
  for (int i = 0; i < 8; ++i)
#pragma unroll
    for (int j = 0; j < 8; ++j) acc[i][j] = 0.f;

  for (int k0 = 0; k0 < K; k0 += GBK) {
    __syncthreads();
#pragma unroll
    for (int q = 0; q < 2; ++q) {
      int i = tid * 2 + q;
      int r = i >> 2, k4 = (i & 3) << 2;
      int pos = start + r;
      int tok = perm ? perm[min(pos, NT_ - 1)] : min(pos, M - 1);
      float4 v = *(const float4*)&X[(size_t)tok * K + k0 + k4];
      As[k4 + 0][r] = v.x; As[k4 + 1][r] = v.y; As[k4 + 2][r] = v.z; As[k4 + 3][r] = v.w;
    }
#pragma unroll
    for (int q = 0; q < 2; ++q) {
      int i = tid * 2 + q;
      int r = i >> 2, k4 = (i & 3) << 2;
      float4 v = *(const float4*)&W[(size_t)(n0 + r) * K + k0 + k4];
      Bs[k4 + 0][r] = v.x; Bs[k4 + 1][r] = v.y; Bs[k4 + 2][r] = v.z; Bs[k4 + 3][r] = v.w;
    }
    __syncthreads();
#pragma unroll
    for (int kk = 0; kk < GBK; ++kk) {
      float4 a0 = *(const float4*)&As[kk][ty * 8];
      float4 a1 = *(const float4*)&As[kk][ty * 8 + 4];
      float4 b0 = *(const float4*)&Bs[kk][tx * 8];
      float4 b1 = *(const float4*)&Bs[kk][tx * 8 + 4];
      float av[8] = {a0.x, a0.y, a0.z, a0.w, a1.x, a1.y, a1.z, a1.w};
      float bv[8] = {b0.x, b0.y, b0.z, b0.w, b1.x, b1.y, b1.z, b1.w};
#pragma unroll
      for (int i = 0; i < 8; ++i)
#pragma unroll
        for (int j = 0; j < 8; ++j) acc[i][j] += av[i] * bv[j];
    }
  }
#pragma unroll
  for (int i = 0; i < 8; ++i) {
    int r = ty * 8 + i;
    if (r >= cnt) continue;
    int tok = perm ? perm[start + r] : (start + r);
    size_t rowoff = (size_t)tok * N + n0 + tx * 8;
    float out[8];
#pragma unroll
    for (int j = 0; j < 8; ++j) {
      float v = acc[i][j] + bias[n0 + tx * 8 + j];
      if (resid) v += resid[rowoff + j];
      if (ACT == 1) v = 0.5f * v * (1.0f + erff(v * 0.70710678118654752f));
      out[j] = v;
    }
    float4 s0; s0.x = out[0]; s0.y = out[1]; s0.z = out[2]; s0.w = out[3];
    float4 s1; s1.x = out[4]; s1.y = out[5]; s1.z = out[6]; s1.w = out[7];
    *(float4*)&Yz[rowoff] = s0;
    *(float4*)&Yz[rowoff + 4] = s1;
  }
}

// ---------------- fp32 flash attention, one (b, head, 32-q-rows) per block ----------------
__global__ __launch_bounds__(256, 2) void attn_kernel(
    const float* __restrict__ Q, const float* __restrict__ Kb, const float* __restrict__ Vb,
    const float* __restrict__ amask, const float* __restrict__ headmask,
    float* __restrict__ ctx, int layer) {
  __shared__ float Qs[32][68];
  __shared__ float Ks[64][68];
  __shared__ float Vs[64][68];
  __shared__ float amk[64];
  int qt = blockIdx.x, hh = blockIdx.y, b = blockIdx.z;
  int tid = threadIdx.x;
  int q0 = qt * 32;
  size_t rowbase = (size_t)b * NS * ND + (size_t)hh * 64;
  for (int i = tid; i < 32 * 64; i += 256) {
    int r = i >> 6, d = i & 63;
    Qs[r][d] = Q[rowbase + (size_t)(q0 + r) * ND + d];
  }
  int r = tid >> 3, cg = tid & 7;
  float o[8] = {0.f, 0.f, 0.f, 0.f, 0.f, 0.f, 0.f, 0.f};
  float mrow = -3.0e38f, lrow = 0.f;
  const float sc = 0.125f;  // 1/sqrt(64)
  for (int kt = 0; kt < 8; ++kt) {
    __syncthreads();
    for (int i = tid; i < 64 * 64; i += 256) {
      int rr = i >> 6, d = i & 63;
      Ks[rr][d] = Kb[rowbase + (size_t)(kt * 64 + rr) * ND + d];
      Vs[rr][d] = Vb[rowbase + (size_t)(kt * 64 + rr) * ND + d];
    }
    if (tid < 64) amk[tid] = amask[b * NS + kt * 64 + tid];
    __syncthreads();
    float p[8];
    float mt = -3.0e38f;
#pragma unroll
    for (int jj = 0; jj < 8; ++jj) {
      int kc = cg + 8 * jj;
      float s = 0.f;
#pragma unroll
      for (int d4 = 0; d4 < 16; ++d4) {
        float4 qv = *(const float4*)&Qs[r][d4 * 4];
        float4 kv = *(const float4*)&Ks[kc][d4 * 4];
        s += qv.x * kv.x + qv.y * kv.y + qv.z * kv.z + qv.w * kv.w;
      }
      s = s * sc + amk[kc];
      p[jj] = s;
      mt = fmaxf(mt, s);
    }
    mt = fmaxf(mt, __shfl_xor(mt, 1, 64));
    mt = fmaxf(mt, __shfl_xor(mt, 2, 64));
    mt = fmaxf(mt, __shfl_xor(mt, 4, 64));
    float mnew = fmaxf(mrow, mt);
    float ps = 0.f;
#pragma unroll
    for (int jj = 0; jj < 8; ++jj) { p[jj] = expf(p[jj] - mnew); ps += p[jj]; }
    ps += __shfl_xor(ps, 1, 64);
    ps += __shfl_xor(ps, 2, 64);
    ps += __shfl_xor(ps, 4, 64);
    float corr = expf(mrow - mnew);
#pragma unroll
    for (int j = 0; j < 8; ++j) o[j] *= corr;
    lrow = lrow * corr + ps;
    mrow = mnew;
#pragma unroll
    for (int k = 0; k < 64; ++k) {
      float pk = __shfl(p[k >> 3], (tid & 56) | (k & 7), 64);
      float4 v0 = *(const float4*)&Vs[k][cg * 8];
      float4 v1 = *(const float4*)&Vs[k][cg * 8 + 4];
      o[0] += pk * v0.x; o[1] += pk * v0.y; o[2] += pk * v0.z; o[3] += pk * v0.w;
      o[4] += pk * v1.x; o[5] += pk * v1.y; o[6] += pk * v1.z; o[7] += pk * v1.w;
    }
  }
  float hm = headmask[layer * NHEAD + hh];
  float inv = hm / lrow;
  size_t obase = rowbase + (size_t)(q0 + r) * ND + cg * 8;
  float4 r0; r0.x = o[0] * inv; r0.y = o[1] * inv; r0.z = o[2] * inv; r0.w = o[3] * inv;
  float4 r1; r1.x = o[4] * inv; r1.y = o[5] * inv; r1.z = o[6] * inv; r1.w = o[7] * inv;
  *(float4*)&ctx[obase] = r0;
  *(float4*)&ctx[obase + 4] = r1;
}

// ---------------- LayerNorm (row of 768), EPS=1e-12 ----------------
__global__ void ln_kernel(const float* __restrict__ xin, const float* __restrict__ g,
                          const float* __restrict__ bta, float* __restrict__ out) {
  int t = blockIdx.x, tid = threadIdx.x;  // 256 threads
  __shared__ float red[8];
  const float* xr = xin + (size_t)t * ND;
  float x0 = xr[tid], x1 = xr[tid + 256], x2 = xr[tid + 512];
  float s = x0 + x1 + x2;
  for (int off = 32; off; off >>= 1) s += __shfl_down(s, off, 64);
  if ((tid & 63) == 0) red[tid >> 6] = s;
  __syncthreads();
  float mu = (red[0] + red[1] + red[2] + red[3]) * (1.0f / 768.0f);
  float d0 = x0 - mu, d1 = x1 - mu, d2 = x2 - mu;
  float v = d0 * d0 + d1 * d1 + d2 * d2;
  for (int off = 32; off; off >>= 1) v += __shfl_down(v, off, 64);
  if ((tid & 63) == 0) red[4 + (tid >> 6)] = v;
  __syncthreads();
  float var = (red[4] + red[5] + red[6] + red[7]) * (1.0f / 768.0f);
  float rs = 1.0f / sqrtf(var + 1e-12f);
  size_t base = (size_t)t * ND;
  out[base + tid] = d0 * rs * g[tid] + bta[tid];
  out[base + tid + 256] = d1 * rs * g[tid + 256] + bta[tid + 256];
  out[base + tid + 512] = d2 * rs * g[tid + 512] + bta[tid + 512];
}

extern "C" void kernel_launch(void* const* d_in, const int* in_sizes, int n_in,
                              void* d_out, int out_size, void* d_ws, size_t ws_size,
                              hipStream_t stream) {
  (void)in_sizes; (void)n_in; (void)out_size;
  const float* hidden = (const float*)d_in[0];
  const float* amask = (const float*)d_in[1];
  const float* hmask = (const float*)d_in[2];
  const float* q_W = (const float*)d_in[3];  const float* q_b = (const float*)d_in[4];
  const float* q_ms = (const float*)d_in[5]; const float* q_gw = (const float*)d_in[6];
  const float* q_gb = (const float*)d_in[7];
  const float* k_W = (const float*)d_in[8];  const float* k_b = (const float*)d_in[9];
  const float* k_ms = (const float*)d_in[10]; const float* k_gw = (const float*)d_in[11];
  const float* k_gb = (const float*)d_in[12];
  const float* v_W = (const float*)d_in[13]; const float* v_b = (const float*)d_in[14];
  const float* v_ms = (const float*)d_in[15]; const float* v_gw = (const float*)d_in[16];
  const float* v_gb = (const float*)d_in[17];
  const float* ao_W = (const float*)d_in[18]; const float* ao_b = (const float*)d_in[19];
  const float* ln1_g = (const float*)d_in[20]; const float* ln1_b = (const float*)d_in[21];
  const float* i_W = (const float*)d_in[22]; const float* i_b = (const float*)d_in[23];
  const float* i_ms = (const float*)d_in[24]; const float* i_gw = (const float*)d_in[25];
  const float* i_gb = (const float*)d_in[26];
  const float* o_W = (const float*)d_in[27]; const float* o_b = (const float*)d_in[28];
  const float* ln2_g = (const float*)d_in[29]; const float* ln2_b = (const float*)d_in[30];

  float* hcur = (float*)d_out;  // hidden state lives in d_out; final layer leaves result
  char* ws = (char*)d_ws;
  size_t off = 0;
  auto alloc = [&](size_t nbytes) -> void* {
    void* p = ws + off;
    off += (nbytes + 255) & ~(size_t)255;
    return p;
  };
  float* p_qkv = (float*)alloc((size_t)3 * NT_ * ND * 4);   // q,k,v outputs
  float* p_ctx = (float*)alloc((size_t)NT_ * ND * 4);
  float* p_attn = (float*)alloc((size_t)NT_ * ND * 4);
  float* p_tmp = (float*)alloc((size_t)NT_ * ND * 4);
  float* p_inter = (float*)alloc((size_t)NT_ * NF * 4);
  float* p_mwqkv = (float*)alloc((size_t)3 * NEXP * NQ * 4);
  float* p_mwi = (float*)alloc((size_t)NEXP * NIMASK * 4);
  uint* p_hist = (uint*)alloc(72 * 256 * 4);
  uint* p_pref = (uint*)alloc(72 * 4);
  uint* p_jrem = (uint*)alloc(72 * 4);
  int* p_e = (int*)alloc((size_t)4 * NT_ * 4);
  int* p_perm = (int*)alloc((size_t)4 * NT_ * 4);
  int* p_meta = (int*)alloc((size_t)4 * 128 * 4);
  (void)ws_size;  // needs ~176 MB

  hipMemcpyAsync(hcur, hidden, (size_t)NT_ * ND * 4, hipMemcpyDeviceToDevice, stream);

  // --- exact top-k thresholds for all 72 masks (4-pass radix select) ---
  radix_init<<<72, 256, 0, stream>>>(p_hist, p_pref, p_jrem);
  for (int pass = 0; pass < 4; ++pass) {
    radix_hist<<<72 * NCHUNK, 256, 0, stream>>>(q_ms, k_ms, v_ms, i_ms, p_pref, p_hist, pass);
    radix_resolve<<<1, 128, 0, stream>>>(p_hist, p_pref, p_jrem, pass);
  }

  for (int l = 0; l < NLAYER; ++l) {
    // masked weights for this layer
    build_mw<<<dim3(1024, 3), 256, 0, stream>>>(q_ms + (size_t)l * 3 * NQ, q_W + (size_t)l * NQ,
                                                p_pref, 0 * 18 + l * 3, p_mwqkv + (size_t)0 * NEXP * NQ, NQ);
    build_mw<<<dim3(1024, 3), 256, 0, stream>>>(k_ms + (size_t)l * 3 * NQ, k_W + (size_t)l * NQ,
                                                p_pref, 1 * 18 + l * 3, p_mwqkv + (size_t)1 * NEXP * NQ, NQ);
    build_mw<<<dim3(1024, 3), 256, 0, stream>>>(v_ms + (size_t)l * 3 * NQ, v_W + (size_t)l * NQ,
                                                p_pref, 2 * 18 + l * 3, p_mwqkv + (size_t)2 * NEXP * NQ, NQ);
    build_mw<<<dim3(2048, 3), 256, 0, stream>>>(i_ms + (size_t)l * 3 * NIMASK, i_W + (size_t)l * NIMASK,
                                                p_pref, 54 + l * 3, p_mwi, NIMASK);
    // gates + routing for q,k,v
    gate_kernel<3><<<NT_, 64, 0, stream>>>(hcur,
        q_gw + (size_t)l * 3 * ND, k_gw + (size_t)l * 3 * ND, v_gw + (size_t)l * 3 * ND,
        q_gb + (size_t)l * 3, k_gb + (size_t)l * 3, v_gb + (size_t)l * 3,
        p_e + 0 * NT_, p_e + 1 * NT_, p_e + 2 * NT_);
    partition_kernel<<<3, 256, 0, stream>>>(p_e, p_perm, p_meta, 0);
    // q,k,v grouped GEMMs batched over z
    gemm_xt<0, 3><<<dim3(MAXT, ND / GBN, 3), 256, 0, stream>>>(
        hcur, p_mwqkv, q_b + (size_t)l * ND, k_b + (size_t)l * ND, v_b + (size_t)l * ND,
        (const float*)0, p_qkv, NT_, ND, ND, p_perm, p_meta);
    // attention
    attn_kernel<<<dim3(16, NHEAD, NB), 256, 0, stream>>>(
        p_qkv, p_qkv + (size_t)NT_ * ND, p_qkv + (size_t)2 * NT_ * ND, amask, hmask, p_ctx, l);
    // ao GEMM + bias + residual(h), then LN1
    gemm_xt<0, 1><<<dim3(NT_ / GBM, ND / GBN, 1), 256, 0, stream>>>(
        p_ctx, ao_W + (size_t)l * NQ, ao_b + (size_t)l * ND, (const float*)0, (const float*)0,
        hcur, p_tmp, NT_, ND, ND, (const int*)0, (const int*)0);
    ln_kernel<<<NT_, 256, 0, stream>>>(p_tmp, ln1_g + (size_t)l * ND, ln1_b + (size_t)l * ND, p_attn);
    // gate + routing for i
    gate_kernel<1><<<NT_, 64, 0, stream>>>(p_attn,
        i_gw + (size_t)l * 3 * ND, (const float*)0, (const float*)0,
        i_gb + (size_t)l * 3, (const float*)0, (const float*)0,
        p_e + 3 * NT_, (int*)0, (int*)0);
    partition_kernel<<<1, 256, 0, stream>>>(p_e, p_perm, p_meta, 3);
    // i grouped GEMM + gelu
    gemm_xt<1, 1><<<dim3(MAXT, NF / GBN, 1), 256, 0, stream>>>(
        p_attn, p_mwi, i_b + (size_t)l * NF, (const float*)0, (const float*)0,
        (const float*)0, p_inter, NT_, NF, ND, p_perm + 3 * NT_, p_meta + 3 * 128);
    // o GEMM + bias + residual(attn_out), then LN2 -> hcur (d_out)
    gemm_xt<0, 1><<<dim3(NT_ / GBM, ND / GBN, 1), 256, 0, stream>>>(
        p_inter, o_W + (size_t)l * ND * NF, o_b + (size_t)l * ND, (const float*)0, (const float*)0,
        p_attn, p_tmp, NT_, ND, NF, (const int*)0, (const int*)0);
    ln_kernel<<<NT_, 256, 0, stream>>>(p_tmp, ln2_g + (size_t)l * ND, ln2_b + (size_t)l * ND, hcur);
  }
}